// Round 1
// baseline (95.001 us; speedup 1.0000x reference)
//
#include <hip/hip_runtime.h>
#include <hip/hip_bf16.h>

// Problem constants (from reference)
#define MAX_LEN_PAD 2560
#define MIN_LEN_SEG 19
#define MAX_NUM_SEG 108   // segments per batch row
#define B_ROWS      32
#define D_DIM       80
#define S_CAND      64
#define N_SEG       3456  // B_ROWS * MAX_NUM_SEG

// ws layout (ints): meta[0..15], seg_start[16..16+3456], seg_off[3536+16 ...]
#define WS_META      0
#define WS_SEGSTART  16
#define WS_SEGOFF    (16 + 3520)

// Kernel A: single block. Computes per-segment offsets (exclusive cumsum of
// len_seg within each batch row), per-segment mask counts (mask is a prefix
// in s -> binary search with the reference's exact fp32 predicate), and the
// global exclusive scan of counts (seg_start). Writes meta {rows, M}.
__global__ __launch_bounds__(1024) void seg_scan_kernel(
    const int* __restrict__ len_seq, const float* __restrict__ scales_u,
    const int* __restrict__ len_seg_raw, int* __restrict__ ws)
{
    __shared__ int lenseg[N_SEG];
    __shared__ int offs[N_SEG];
    __shared__ int cnts[N_SEG];
    __shared__ int scan[1024];

    int tid = threadIdx.x;
    for (int i = tid; i < N_SEG; i += 1024) lenseg[i] = len_seg_raw[i] + MIN_LEN_SEG;
    __syncthreads();

    // exclusive cumsum of len_seg within each batch row (32 rows x 108)
    if (tid < B_ROWS) {
        int off = 0;
        int base = tid * MAX_NUM_SEG;
        for (int j = 0; j < MAX_NUM_SEG; ++j) {
            offs[base + j] = off;
            off += lenseg[base + j];
        }
    }
    __syncthreads();

    // per-segment count: first s in [0,64) where mask fails (mask is prefix).
    // Predicate replicated with the reference's exact fp32 ops.
    for (int i = tid; i < N_SEG; i += 1024) {
        float scale = scales_u[i] + 0.5f;
        int T = lenseg[i] - 1;
        int lim = len_seq[i / MAX_NUM_SEG] - 1 - offs[i];
        if (lim < T) T = lim;
        float Tf = (float)T;
        int lo = 0, hi = S_CAND;
        while (lo < hi) {
            int mid = (lo + hi) >> 1;
            float fi = floorf((float)mid / scale);   // exact IEEE div + floor, matches ref
            if (fi < Tf) lo = mid + 1; else hi = mid;
        }
        cnts[i] = lo;
    }
    __syncthreads();

    // exclusive scan of cnts over N_SEG: 4 per thread + Hillis-Steele over 1024
    int c0 = 0;
    int base4 = tid * 4;
    #pragma unroll
    for (int j = 0; j < 4; ++j) {
        int k = base4 + j;
        if (k < N_SEG) c0 += cnts[k];
    }
    scan[tid] = c0;
    __syncthreads();
    for (int off = 1; off < 1024; off <<= 1) {
        int v = scan[tid];
        if (tid >= off) v += scan[tid - off];
        __syncthreads();
        scan[tid] = v;
        __syncthreads();
    }
    int total = scan[1023];
    int excl = scan[tid] - c0;  // exclusive base of this thread's 4-chunk

    int* seg_start = ws + WS_SEGSTART;
    int* seg_off   = ws + WS_SEGOFF;
    int run = excl;
    #pragma unroll
    for (int j = 0; j < 4; ++j) {
        int k = base4 + j;
        if (k < N_SEG) { seg_start[k] = run; run += cnts[k]; }
    }
    if (tid == 0) {
        seg_start[N_SEG] = total;
        int rows = total / B_ROWS;
        int M = rows < MAX_LEN_PAD ? rows : MAX_LEN_PAD;
        ws[WS_META + 0] = rows;
        ws[WS_META + 1] = M;
    }
    for (int i = tid; i < N_SEG; i += 1024) seg_off[i] = offs[i];
}

// Kernel B: each block handles 16 output rows (16 x 20 float4 = 320 threads).
// Threads 0..15 binary-search the compaction inverse for their row and stash
// (src_row, lam) in LDS; then all threads do coalesced float4 lerp / zero.
__global__ __launch_bounds__(320) void fill_kernel(
    const float* __restrict__ x, const float* __restrict__ scales_u,
    const int* __restrict__ ws, float* __restrict__ out)
{
    __shared__ int   s_src[16];
    __shared__ float s_lam[16];

    const int* meta      = ws + WS_META;
    const int* seg_start = ws + WS_SEGSTART;
    const int* seg_off   = ws + WS_SEGOFF;

    int tid = threadIdx.x;
    int r_base = blockIdx.x * 16;
    int rows = meta[0];
    int M    = meta[1];

    if (tid < 16) {
        int r = r_base + tid;
        int b = r / MAX_LEN_PAD;
        int t = r - b * MAX_LEN_PAD;
        int src = -1;
        float lam = 0.0f;
        if (t < M) {
            int g = b * rows + t;   // compacted index; g < total guaranteed
            // first n with seg_start[n+1] > g
            int lo = 0, hi = N_SEG;
            while (lo < hi) {
                int mid = (lo + hi) >> 1;
                if (seg_start[mid + 1] <= g) lo = mid + 1; else hi = mid;
            }
            int n = lo;
            int s = g - seg_start[n];           // position within segment (prefix order)
            float scale = scales_u[n] + 0.5f;
            float q = (float)s / scale;
            float fi = floorf(q);
            lam = q - fi;
            int idx_org = (int)fi + seg_off[n];
            int i_fl = idx_org;
            if (i_fl < 0) i_fl = 0;
            if (i_fl > MAX_LEN_PAD - 2) i_fl = MAX_LEN_PAD - 2;
            src = (n / MAX_NUM_SEG) * MAX_LEN_PAD + i_fl;  // source batch row of the SEGMENT
        }
        s_src[tid] = src;
        s_lam[tid] = lam;
    }
    __syncthreads();

    int rl = tid / 20;
    int q4 = tid - rl * 20;
    int r  = r_base + rl;
    int   src = s_src[rl];
    float lam = s_lam[rl];

    float4 res;
    if (src < 0) {
        res = make_float4(0.f, 0.f, 0.f, 0.f);
    } else {
        const float4* x4 = (const float4*)x;
        float4 a = x4[src * 20 + q4];
        float4 c = x4[src * 20 + 20 + q4];
        float om = 1.0f - lam;
        res.x = om * a.x + lam * c.x;
        res.y = om * a.y + lam * c.y;
        res.z = om * a.z + lam * c.z;
        res.w = om * a.w + lam * c.w;
    }
    ((float4*)out)[r * 20 + q4] = res;
}

extern "C" void kernel_launch(void* const* d_in, const int* in_sizes, int n_in,
                              void* d_out, int out_size, void* d_ws, size_t ws_size,
                              hipStream_t stream) {
    (void)in_sizes; (void)n_in; (void)out_size; (void)ws_size;
    const float* x           = (const float*)d_in[0];
    const int*   len_seq     = (const int*)d_in[1];
    const float* scales_u    = (const float*)d_in[2];
    const int*   len_seg_raw = (const int*)d_in[3];
    float* out = (float*)d_out;
    int*   ws  = (int*)d_ws;

    seg_scan_kernel<<<1, 1024, 0, stream>>>(len_seq, scales_u, len_seg_raw, ws);

    // 32*2560 rows / 16 rows per block = 5120 blocks
    fill_kernel<<<5120, 320, 0, stream>>>(x, scales_u, ws, out);
}

// Round 2
// 88.313 us; speedup vs baseline: 1.0757x; 1.0757x over previous
//
#include <hip/hip_runtime.h>
#include <hip/hip_bf16.h>

// Problem constants (from reference)
#define MAX_LEN_PAD 2560
#define MIN_LEN_SEG 19
#define MAX_NUM_SEG 108   // segments per batch row
#define B_ROWS      32
#define S_CAND      64
#define N_SEG       3456  // B_ROWS * MAX_NUM_SEG

// ws layout (ints): meta[0..15], seg_start[16..16+3456], seg_off after
#define WS_META      0
#define WS_SEGSTART  16
#define WS_SEGOFF    (16 + 3520)

// Kernel A: single block, 1024 threads.
//  - per-batch-row exclusive cumsum of len_seg via 32-lane shfl scans (offsets)
//  - per-segment mask counts (mask is a prefix in s -> 6-step binary search
//    with the reference's exact fp32 predicate), 4 segments/thread
//  - global exclusive scan of counts via wave shfl scan + tiny LDS combine
//  Only 3 __syncthreads total (vs 20+ in the Hillis-Steele version).
__global__ __launch_bounds__(1024) void seg_scan_kernel(
    const int* __restrict__ len_seq, const float* __restrict__ scales_u,
    const int* __restrict__ len_seg_raw, int* __restrict__ ws)
{
    __shared__ int lenseg[N_SEG];
    __shared__ int offs[N_SEG];
    __shared__ int wavesum[24];

    int tid = threadIdx.x;
    for (int i = tid; i < N_SEG; i += 1024) lenseg[i] = len_seg_raw[i] + MIN_LEN_SEG;
    __syncthreads();

    // per-row exclusive cumsum: one 32-lane group per batch row (32 rows x 108)
    {
        int row = tid >> 5, l32 = tid & 31;
        int base = row * MAX_NUM_SEG;
        int v[4]; int sum = 0;
        #pragma unroll
        for (int j = 0; j < 4; ++j) {
            int k = l32 * 4 + j;
            v[j] = (k < MAX_NUM_SEG) ? lenseg[base + k] : 0;
            sum += v[j];
        }
        int incl = sum;
        #pragma unroll
        for (int d = 1; d < 32; d <<= 1) {
            int o = __shfl_up(incl, d, 32);
            if (l32 >= d) incl += o;
        }
        int run = incl - sum;   // exclusive base for this lane's chunk
        #pragma unroll
        for (int j = 0; j < 4; ++j) {
            int k = l32 * 4 + j;
            if (k < MAX_NUM_SEG) { offs[base + k] = run; run += v[j]; }
        }
    }
    __syncthreads();

    // counts: 4 consecutive segments per thread (3456 = 864*4)
    int cnt[4] = {0, 0, 0, 0};
    int csum = 0;
    if (tid < N_SEG / 4) {
        float4 sc4 = ((const float4*)scales_u)[tid];
        float scv[4] = {sc4.x, sc4.y, sc4.z, sc4.w};
        #pragma unroll
        for (int j = 0; j < 4; ++j) {
            int k = tid * 4 + j;
            float scale = scv[j] + 0.5f;
            int T = lenseg[k] - 1;
            int lim = len_seq[k / MAX_NUM_SEG] - 1 - offs[k];
            if (lim < T) T = lim;
            float Tf = (float)T;
            int lo = 0, hi = S_CAND;
            while (lo < hi) {
                int mid = (lo + hi) >> 1;
                // exact IEEE div + floor, matches the reference's predicate
                if (floorf((float)mid / scale) < Tf) lo = mid + 1; else hi = mid;
            }
            cnt[j] = lo; csum += lo;
        }
    }

    // block-wide exclusive scan of csum: wave shfl scan + 16-entry combine
    int lane = tid & 63, wave = tid >> 6;
    int incl = csum;
    #pragma unroll
    for (int d = 1; d < 64; d <<= 1) {
        int o = __shfl_up(incl, d, 64);
        if (lane >= d) incl += o;
    }
    if (lane == 63) wavesum[wave] = incl;
    __syncthreads();
    if (tid == 0) {
        int run = 0;
        #pragma unroll
        for (int w = 0; w < 16; ++w) { int v = wavesum[w]; wavesum[w] = run; run += v; }
        wavesum[16] = run;   // total
    }
    __syncthreads();
    int excl = wavesum[wave] + incl - csum;

    int* seg_start = ws + WS_SEGSTART;
    int* seg_off   = ws + WS_SEGOFF;
    if (tid < N_SEG / 4) {
        int4 st;
        st.x = excl;
        st.y = st.x + cnt[0];
        st.z = st.y + cnt[1];
        st.w = st.z + cnt[2];
        ((int4*)seg_start)[tid] = st;
    }
    for (int i = tid; i < N_SEG; i += 1024) seg_off[i] = offs[i];
    if (tid == 0) {
        int total = wavesum[16];
        seg_start[N_SEG] = total;
        int rows = total / B_ROWS;
        int M = rows < MAX_LEN_PAD ? rows : MAX_LEN_PAD;
        ws[WS_META + 0] = rows;
        ws[WS_META + 1] = M;
    }
}

// Kernel B: segment-parallel direct scatter + fused zero-fill.
// Block n (< 3456) owns segment n: for each s < cnt_n, compacted index
// g = seg_start[n]+s lands at out row (g/rows, g%rows) — written directly,
// no binary search. 16 s-values x 20 float4 lanes = 320 threads.
// All 5120 blocks also zero their 16-row slice where t >= M (out is poisoned).
__global__ __launch_bounds__(320) void scatter_fill_kernel(
    const float* __restrict__ x, const float* __restrict__ scales_u,
    const int* __restrict__ ws, float* __restrict__ out)
{
    const int* meta      = ws + WS_META;
    const int* seg_start = ws + WS_SEGSTART;
    const int* seg_off   = ws + WS_SEGOFF;

    int rows = meta[0];
    int M    = meta[1];
    int tid  = threadIdx.x;
    int rl   = tid / 20;
    int q4   = tid - rl * 20;
    const float4* x4   = (const float4*)x;
    float4*       out4 = (float4*)out;

    int n = blockIdx.x;
    if (n < N_SEG && rows > 0) {
        int s0  = seg_start[n];          // wave-uniform -> scalar loads
        int cnt = seg_start[n + 1] - s0;
        if (cnt > 0) {
            float scale = scales_u[n] + 0.5f;
            int off  = seg_off[n];
            int xrow = (n / MAX_NUM_SEG) * MAX_LEN_PAD;
            for (int s = rl; s < cnt; s += 16) {
                int g = s0 + s;
                int b_out = g / rows;
                if (b_out < B_ROWS) {
                    int t = g - b_out * rows;
                    if (t < MAX_LEN_PAD) {
                        float q  = (float)s / scale;
                        float fi = floorf(q);
                        float lam = q - fi;
                        int i_fl = (int)fi + off;
                        if (i_fl > MAX_LEN_PAD - 2) i_fl = MAX_LEN_PAD - 2; // ref clip (no-op for kept elems)
                        int sb = (xrow + i_fl) * 20 + q4;
                        float4 a = x4[sb];
                        float4 c = x4[sb + 20];
                        float om = 1.0f - lam;
                        float4 r;
                        r.x = om * a.x + lam * c.x;
                        r.y = om * a.y + lam * c.y;
                        r.z = om * a.z + lam * c.z;
                        r.w = om * a.w + lam * c.w;
                        out4[(b_out * MAX_LEN_PAD + t) * 20 + q4] = r;
                    }
                }
            }
        }
    }

    // zero-fill phase: this block's 16 output rows, where t >= M
    int r = blockIdx.x * 16 + rl;
    int t = (blockIdx.x % (MAX_LEN_PAD / 16)) * 16 + rl;  // 2560 % 16 == 0
    if (t >= M) out4[r * 20 + q4] = make_float4(0.f, 0.f, 0.f, 0.f);
}

extern "C" void kernel_launch(void* const* d_in, const int* in_sizes, int n_in,
                              void* d_out, int out_size, void* d_ws, size_t ws_size,
                              hipStream_t stream) {
    (void)in_sizes; (void)n_in; (void)out_size; (void)ws_size;
    const float* x           = (const float*)d_in[0];
    const int*   len_seq     = (const int*)d_in[1];
    const float* scales_u    = (const float*)d_in[2];
    const int*   len_seg_raw = (const int*)d_in[3];
    float* out = (float*)d_out;
    int*   ws  = (int*)d_ws;

    seg_scan_kernel<<<1, 1024, 0, stream>>>(len_seq, scales_u, len_seg_raw, ws);

    // 32*2560 rows / 16 rows per block = 5120 blocks (blocks 0..3455 also scatter)
    scatter_fill_kernel<<<5120, 320, 0, stream>>>(x, scales_u, ws, out);
}